// Round 14
// baseline (387.549 us; speedup 1.0000x reference)
//
#include <hip/hip_runtime.h>

#define N_NODES 100000
#define N_EDGES 3200000
#define BATCH 16
#define BKT_SHIFT 6
#define BKT_NODES 64
#define K_BUCKETS 1563                 // ceil(100000/64)
#define NB 256                         // subchunks (E/NB = 12500 exact)
#define SUB (N_EDGES / NB)             // 12500
#define HSPLIT 4                       // hist blocks per subchunk
#define HSUB (SUB / HSPLIT)            // 3125
#define FT 512                         // fill threads (round-9 proven; 1024 FAILED replay validation)
#define SCAN_T 256
#define SCAN_C 7                       // 256*7 = 1792 >= 1563
#define CAP 4096                       // nodesort LDS capacity (bucket avg 2047, sigma 45)
#define NT 512                         // nodesort threads (was 256; stride-parametrized only)
#define PD 8                           // pull pipeline depth (12 was neutral->negative; 8 proven)
#define CS_BPB 16                      // colscan buckets per block

// ---- phase 1: per-subchunk histogram, 4 blocks per subchunk ----
// 1024 blocks (16 waves/CU vs 4 before) merge into the SAME blk_cnt[k][s]
// layout via global atomicAdd (blk_cnt pre-zeroed; zero counters skipped).
__global__ void hist_kernel(const int* __restrict__ row, int* __restrict__ blk_cnt) {
    __shared__ int lh[K_BUCKETS];
    int t = threadIdx.x, blk = blockIdx.x;
    int s = blk >> 2;                  // subchunk
    int q = blk & 3;                   // quarter
    for (int k = t; k < K_BUCKETS; k += 256) lh[k] = 0;
    __syncthreads();
    int base = s * SUB + q * HSUB;
    for (int e = base + t; e < base + HSUB; e += 256)
        atomicAdd(&lh[row[e] >> BKT_SHIFT], 1);
    __syncthreads();
    for (int k = t; k < K_BUCKETS; k += 256) {
        int v = lh[k];
        if (v) atomicAdd(&blk_cnt[k * NB + s], v);
    }
}

// ---- phase 2: per-bucket exclusive prefix over the NB subchunks; totals ----
// 16 threads per bucket (16 segments of 16 ints): 98 blocks x 256 threads.
__global__ void colscan_kernel(int* __restrict__ blk_cnt, int* __restrict__ totals) {
    __shared__ int seg[CS_BPB][16];
    int t = threadIdx.x;
    int lb = t >> 4;                   // bucket within block
    int sg = t & 15;                   // segment within bucket row
    int bkt = blockIdx.x * CS_BPB + lb;
    bool ok = bkt < K_BUCKETS;
    int4 v[4];
    int sum = 0;
    int4* p = nullptr;
    if (ok) {
        p = (int4*)&blk_cnt[bkt * NB + sg * 16];
        #pragma unroll
        for (int qq = 0; qq < 4; qq++) {
            v[qq] = p[qq];
            sum += v[qq].x + v[qq].y + v[qq].z + v[qq].w;
        }
    }
    seg[lb][sg] = sum;
    __syncthreads();
    if (sg == 0 && ok) {
        int acc = 0;
        #pragma unroll
        for (int i = 0; i < 16; i++) {
            int x = seg[lb][i];
            seg[lb][i] = acc;
            acc += x;
        }
        totals[bkt] = acc;
    }
    __syncthreads();
    if (ok) {
        int acc = seg[lb][sg];
        #pragma unroll
        for (int qq = 0; qq < 4; qq++) {
            int4 o;
            o.x = acc; acc += v[qq].x;
            o.y = acc; acc += v[qq].y;
            o.z = acc; acc += v[qq].z;
            o.w = acc; acc += v[qq].w;
            p[qq] = o;
        }
    }
}

// ---- phase 3: exclusive scan of 1563 bucket totals -> bptr ----
__global__ void scan_kernel(const int* __restrict__ totals, int* __restrict__ bptr,
                            int* __restrict__ row_ptr) {
    __shared__ int s[SCAN_T];
    int t = threadIdx.x;
    int loc[SCAN_C];
    int sum = 0;
    for (int i = 0; i < SCAN_C; i++) {
        int idx = t * SCAN_C + i;
        int v = (idx < K_BUCKETS) ? totals[idx] : 0;
        loc[i] = v;
        sum += v;
    }
    s[t] = sum;
    __syncthreads();
    for (int off = 1; off < SCAN_T; off <<= 1) {   // Hillis-Steele inclusive
        int x = (t >= off) ? s[t - off] : 0;
        __syncthreads();
        s[t] += x;
        __syncthreads();
    }
    int excl = s[t] - sum;
    for (int i = 0; i < SCAN_C; i++) {
        int idx = t * SCAN_C + i;
        if (idx < K_BUCKETS) bptr[idx] = excl;
        excl += loc[i];
    }
    if (t == 0) { bptr[K_BUCKETS] = N_EDGES; row_ptr[N_NODES] = N_EDGES; }
}

// ---- phase 4: LDS counting sort per 12500-edge subchunk, then run copy-out.
// record: x = (r_local<<17)|col (col<2^17), y = w bits.
// BYTE-IDENTICAL to round 9 (FT=512, replay-proven; FT=1024 failed replays).
__global__ void __launch_bounds__(FT) fill_kernel(
        const int* __restrict__ row, const int* __restrict__ col,
        const float* __restrict__ w,
        const int* __restrict__ bptr, const int* __restrict__ blk_cnt,
        uint2* __restrict__ entries) {
    __shared__ uint2 sbuf[SUB];          // 100000 B
    __shared__ int lbeg[K_BUCKETS];      // 6252 B
    __shared__ int lcur[K_BUCKETS];      // 6252 B
    __shared__ int sscan[FT];            // 2048 B   (total 114.5 KB)
    int t = threadIdx.x, blk = blockIdx.x;
    for (int k = t; k < K_BUCKETS; k += FT) lcur[k] = 0;
    __syncthreads();
    int base = blk * SUB;
    // pass 1: histogram into lcur
    for (int e = base + t; e < base + SUB; e += FT)
        atomicAdd(&lcur[row[e] >> BKT_SHIFT], 1);
    __syncthreads();
    // block-wide exclusive scan (each thread owns 4 buckets)
    int loc[4];
    int sum = 0;
    #pragma unroll
    for (int j = 0; j < 4; j++) {
        int k = t * 4 + j;
        int v = (k < K_BUCKETS) ? lcur[k] : 0;
        loc[j] = v;
        sum += v;
    }
    sscan[t] = sum;
    __syncthreads();
    for (int off = 1; off < FT; off <<= 1) {
        int x = (t >= off) ? sscan[t - off] : 0;
        __syncthreads();
        sscan[t] += x;
        __syncthreads();
    }
    int excl = sscan[t] - sum;
    #pragma unroll
    for (int j = 0; j < 4; j++) {
        int k = t * 4 + j;
        if (k < K_BUCKETS) { lbeg[k] = excl; lcur[k] = excl; }
        excl += loc[j];
    }
    __syncthreads();
    // pass 2: place records into LDS (bucket-sorted)
    for (int e = base + t; e < base + SUB; e += FT) {
        int r = row[e];
        int bkt = r >> BKT_SHIFT;
        int pos = atomicAdd(&lcur[bkt], 1);
        sbuf[pos] = make_uint2(((unsigned)(r & (BKT_NODES - 1)) << 17) | (unsigned)col[e],
                               __float_as_uint(w[e]));
    }
    __syncthreads();
    // pass 3: 8-lane subgroups copy each bucket run out (coalesced per run)
    int lane = t & 7;
    for (int k = (t >> 3); k < K_BUCKETS; k += FT / 8) {
        int lb = lbeg[k];
        int le = lcur[k];
        int dst = bptr[k] + blk_cnt[k * NB + blk];
        for (int i = lb + lane; i < le; i += 8)
            entries[dst + (i - lb)] = sbuf[i];
    }
}

// ---- phase 5: in-place per-bucket sort by node (LDS-staged); emits row_ptr ----
// NT=512 (was 256): stride-parametrized only, no structural change; 4
// blocks/CU x 8 waves = full occupancy, per-thread iterations halve.
__global__ void __launch_bounds__(NT) nodesort_kernel(
        const int* __restrict__ bptr, uint2* __restrict__ entries,
        int* __restrict__ row_ptr) {
    __shared__ uint2 ebuf[CAP];          // 32 KB
    __shared__ int nh[BKT_NODES];
    __shared__ int nc[BKT_NODES];
    int t = threadIdx.x, b = blockIdx.x;
    int beg = bptr[b], end = bptr[b + 1];
    int n = min(end - beg, CAP);
    if (t < BKT_NODES) nh[t] = 0;
    __syncthreads();
    for (int k = t; k < n; k += NT) {
        uint2 r = entries[beg + k];
        ebuf[k] = r;
        atomicAdd(&nh[r.x >> 17], 1);
    }
    __syncthreads();
    if (t == 0) {
        int acc = 0;
        for (int i = 0; i < BKT_NODES; i++) {
            int v = nh[i];
            int node = b * BKT_NODES + i;
            if (node < N_NODES) row_ptr[node] = beg + acc;
            nc[i] = acc;
            acc += v;
        }
    }
    __syncthreads();
    for (int k = t; k < n; k += NT) {
        uint2 r = ebuf[k];
        int pos = atomicAdd(&nc[r.x >> 17], 1);
        entries[beg + pos] = r;
    }
}

// ---- layer: node-parallel CSR pull, 8-deep software pipeline, masked epilogue
// (byte-identical to round 9's pull — measured best: PD=12 neutral, nt worse)
__global__ void __launch_bounds__(256) pull_kernel(const float* __restrict__ y,
                            const uint2* __restrict__ entries,
                            const int* __restrict__ row_ptr,
                            float* __restrict__ out) {
    int tid = blockIdx.x * blockDim.x + threadIdx.x;
    int node = tid >> 4;
    int b = tid & 15;
    if (node >= N_NODES) return;
    int beg = row_ptr[node];
    int end = row_ptr[node + 1];
    float acc = 0.f;
    if (beg < end) {
        int lim = end - 1;
        uint2 r[PD];
        #pragma unroll
        for (int j = 0; j < PD; j++) r[j] = entries[min(beg + j, lim)];
        int i = beg;
        while (i + PD <= end) {
            float yv[PD];
            #pragma unroll
            for (int j = 0; j < PD; j++)
                yv[j] = y[(r[j].x & 0x1FFFFu) * BATCH + b];
            uint2 nx[PD];
            #pragma unroll
            for (int j = 0; j < PD; j++)
                nx[j] = entries[min(i + PD + j, lim)];
            #pragma unroll
            for (int j = 0; j < PD; j++)
                acc += __uint_as_float(r[j].y) * yv[j];
            #pragma unroll
            for (int j = 0; j < PD; j++) r[j] = nx[j];
            i += PD;
        }
        if (i < end) {                       // masked epilogue, still batched
            float yv[PD];
            #pragma unroll
            for (int j = 0; j < PD; j++)
                yv[j] = y[(r[j].x & 0x1FFFFu) * BATCH + b];
            #pragma unroll
            for (int j = 0; j < PD; j++)
                if (i + j < end)
                    acc += __uint_as_float(r[j].y) * yv[j];
        }
    }
    out[node * BATCH + b] = acc;
}

extern "C" void kernel_launch(void* const* d_in, const int* in_sizes, int n_in,
                              void* d_out, int out_size, void* d_ws, size_t ws_size,
                              hipStream_t stream) {
    const float* x   = (const float*)d_in[0];
    const float* w   = (const float*)d_in[1];
    const int*   row = (const int*)d_in[2];
    const int*   col = (const int*)d_in[3];
    float*       out = (float*)d_out;

    // ---- workspace carve-up (~32.4 MB; proven ws >= 33.2 MB) ----
    char* p = (char*)d_ws;
    uint2* entries = (uint2*)p;  p += (size_t)N_EDGES * sizeof(uint2);           // 25.6 MB
    float* buf     = (float*)p;                                                   // 6.4 MB
    int*   blk_cnt = (int*)buf;  // 1.6 MB alias: dead before first pull writes buf
    p += (size_t)N_NODES * BATCH * sizeof(float);
    int* totals  = (int*)p;      p += 8192;
    int* bptr    = (int*)p;      p += 8192;
    int* row_ptr = (int*)p;      // 400 KB

    // ---- build exact per-node CSR (once; reused by all 4 layers) ----
    hipMemsetAsync(blk_cnt, 0, (size_t)K_BUCKETS * NB * sizeof(int), stream);
    hist_kernel<<<NB * HSPLIT, 256, 0, stream>>>(row, blk_cnt);
    colscan_kernel<<<(K_BUCKETS + CS_BPB - 1) / CS_BPB, 256, 0, stream>>>(blk_cnt, totals);
    scan_kernel<<<1, SCAN_T, 0, stream>>>(totals, bptr, row_ptr);
    fill_kernel<<<NB, FT, 0, stream>>>(row, col, w, bptr, blk_cnt, entries);
    nodesort_kernel<<<K_BUCKETS, NT, 0, stream>>>(bptr, entries, row_ptr);

    // ---- 4 pull layers; d_out doubles as ping-pong buffer, no memsets ----
    const int pgrid = (N_NODES * BATCH + 255) / 256;   // 6250 blocks
    pull_kernel<<<pgrid, 256, 0, stream>>>(x,   entries, row_ptr, buf);  // x   -> buf
    pull_kernel<<<pgrid, 256, 0, stream>>>(buf, entries, row_ptr, out);  // buf -> out
    pull_kernel<<<pgrid, 256, 0, stream>>>(out, entries, row_ptr, buf);  // out -> buf
    pull_kernel<<<pgrid, 256, 0, stream>>>(buf, entries, row_ptr, out);  // buf -> out
}